// Round 11
// baseline (243.238 us; speedup 1.0000x reference)
//
#include <hip/hip_runtime.h>
#include <hip/hip_bf16.h>

// Problem constants (set_attention): B=4, Nq=Nk=2048, D_IN=512, H=8, HS=64
#define BB   4
#define NQ   2048
#define NKK  2048
#define DIN  512
#define NH   8
#define HS   64
#define HD   512  // NH*HS

typedef __hip_bfloat16 bf16;
typedef unsigned short ushort_t;
typedef __attribute__((ext_vector_type(8))) short short8;  // 8 bf16 (4 VGPRs)
typedef __attribute__((ext_vector_type(4))) float f32x4;   // MFMA C/D

__device__ __forceinline__ unsigned short f2bu(float x) {
  bf16 h = __float2bfloat16(x);
  return *(unsigned short*)&h;
}

// ---------------------------------------------------------------------------
// Kernel 0a: f32 -> bf16 convert of the two activations (q, k).
// Cuts proj's A-fetch 4x (r5 counter: FETCH 199MB from f32 X re-reads).
// ---------------------------------------------------------------------------
__global__ __launch_bounds__(256) void cvt_kernel(
    const float* __restrict__ q, const float* __restrict__ k,
    ushort_t* __restrict__ Xb) {
  const float* src = blockIdx.y ? k : q;
  ushort_t* dst = Xb + (size_t)blockIdx.y * 8192 * 512;
  size_t i = ((size_t)blockIdx.x * 256 + threadIdx.x) * 4;
  float4 v = *(const float4*)(src + i);
  __align__(8) ushort_t t4[4] = {f2bu(v.x), f2bu(v.y), f2bu(v.z), f2bu(v.w)};
  *(uint2*)(dst + i) = *(uint2*)t4;
}

// ---------------------------------------------------------------------------
// Kernel 0b: weight transpose + bf16 convert.
// z<3:  W[512k][512n] f32 -> Wt_z[n][k] bf16   (64x64 tiles via LDS)
// z==3: Wh[512k][64n] f32 -> Wht[n][k] bf16
// ---------------------------------------------------------------------------
__global__ __launch_bounds__(256) void wtrans_kernel(
    const float* __restrict__ Wq, const float* __restrict__ Wk,
    const float* __restrict__ Wv, const float* __restrict__ Wh,
    ushort_t* __restrict__ Wt, ushort_t* __restrict__ Wht) {
  const int z = blockIdx.z;
  const float* src;
  ushort_t* dst;
  int S;
  if (z < 3) {
    src = (z == 0) ? Wq : (z == 1) ? Wk : Wv;
    dst = Wt + (size_t)z * 512 * 512;
    S = 512;
  } else {
    if (blockIdx.y != 0) return;
    src = Wh;
    dst = Wht;
    S = 64;
  }
  const int k0 = blockIdx.x * 64;
  const int n0 = (z < 3) ? blockIdx.y * 64 : 0;

  __shared__ ushort_t Ls[64 * 72];
  const int tid = threadIdx.x;
  {
    int r = tid >> 2, cb = (tid & 3) * 16;
    const float* sp = src + (size_t)(k0 + r) * S + n0 + cb;
#pragma unroll
    for (int ii = 0; ii < 4; ++ii) {
      float4 f = *(const float4*)(sp + ii * 4);
      __align__(8) ushort_t t4[4] = {f2bu(f.x), f2bu(f.y), f2bu(f.z), f2bu(f.w)};
      *(uint2*)(&Ls[r * 72 + cb + ii * 4]) = *(uint2*)t4;
    }
  }
  __syncthreads();
  {
    int rr = tid >> 2, tb = (tid & 3) * 16;
    __align__(16) ushort_t tmp[16];
#pragma unroll
    for (int j = 0; j < 16; ++j) tmp[j] = Ls[(tb + j) * 72 + rr];
    ushort_t* dp = dst + (size_t)(n0 + rr) * 512 + k0 + tb;
    *(int4*)dp       = ((int4*)tmp)[0];
    *(int4*)(dp + 8) = ((int4*)tmp)[1];
  }
}

// ---------------------------------------------------------------------------
// Kernel 1: QKV projections, bf16 MFMA, double-buffered. 128x128 tile, BK=32,
// grid (4,64,3)=768 blocks (r6-proven shape). Both operands bf16 (Xb from
// cvt, Wt pre-transposed [n][k]): staging is pure int4 copies.
// ---------------------------------------------------------------------------
__global__ __launch_bounds__(256) void proj_kernel(
    const ushort_t* __restrict__ Xb, const ushort_t* __restrict__ Wt,
    ushort_t* __restrict__ Qf, ushort_t* __restrict__ Kf,
    ushort_t* __restrict__ Vf) {
  const int z = blockIdx.z;
  const ushort_t* Xz = Xb + (size_t)(z ? 1 : 0) * 8192 * 512;
  const ushort_t* Wz = Wt + (size_t)z * 512 * 512;
  ushort_t* Y = (z == 0) ? Qf : (z == 1) ? Kf : Vf;
  const float sc = (z == 0) ? 0.125f : 1.0f;  // fold 1/sqrt(64) into Q

  __shared__ ushort_t As[2 * 128 * 40];  // [buf][m][k]
  __shared__ ushort_t Bs[2 * 128 * 40];  // [buf][n][k]

  const int tid  = threadIdx.x;
  const int lane = tid & 63;
  const int w    = tid >> 6;
  const int quad = lane >> 4;
  const int c    = lane & 15;
  const int wm   = w >> 1, wn = w & 1;

  const int m0 = blockIdx.y * 128;
  const int n0 = blockIdx.x * 128;
  const int sm  = tid >> 1;
  const int skb = (tid & 1) * 16;

  int4 xa[2], wb[2];
  auto load_t = [&](int k0) {
    const ushort_t* xp = Xz + (size_t)(m0 + sm) * DIN + k0 + skb;
    xa[0] = *(const int4*)xp;
    xa[1] = *(const int4*)(xp + 8);
    const ushort_t* wp = Wz + (size_t)(n0 + sm) * 512 + k0 + skb;
    wb[0] = *(const int4*)wp;
    wb[1] = *(const int4*)(wp + 8);
  };
  auto store_t = [&](int buf) {
    *(int4*)(&As[buf * 5120 + sm * 40 + skb])     = xa[0];
    *(int4*)(&As[buf * 5120 + sm * 40 + skb + 8]) = xa[1];
    *(int4*)(&Bs[buf * 5120 + sm * 40 + skb])     = wb[0];
    *(int4*)(&Bs[buf * 5120 + sm * 40 + skb + 8]) = wb[1];
  };

  f32x4 acc[4][4];
#pragma unroll
  for (int m = 0; m < 4; ++m)
#pragma unroll
    for (int n = 0; n < 4; ++n) acc[m][n] = (f32x4)0.0f;

  load_t(0);
  store_t(0);
  __syncthreads();

  for (int t = 0; t < 16; ++t) {
    const int cur = t & 1;
    if (t < 15) load_t((t + 1) * 32);
    const ushort_t* as = As + cur * 5120;
    const ushort_t* bs = Bs + cur * 5120;
    short8 af[4], bfr[4];
#pragma unroll
    for (int m = 0; m < 4; ++m)
      af[m] = *(const short8*)(&as[(wm * 64 + m * 16 + c) * 40 + quad * 8]);
#pragma unroll
    for (int n = 0; n < 4; ++n)
      bfr[n] = *(const short8*)(&bs[(wn * 64 + n * 16 + c) * 40 + quad * 8]);
#pragma unroll
    for (int m = 0; m < 4; ++m)
#pragma unroll
      for (int n = 0; n < 4; ++n)
        acc[m][n] = __builtin_amdgcn_mfma_f32_16x16x32_bf16(af[m], bfr[n], acc[m][n], 0, 0, 0);
    if (t < 15) store_t(cur ^ 1);
    __syncthreads();
  }

#pragma unroll
  for (int m = 0; m < 4; ++m)
#pragma unroll
    for (int n = 0; n < 4; ++n)
#pragma unroll
      for (int r = 0; r < 4; ++r) {
        int row = m0 + wm * 64 + m * 16 + quad * 4 + r;
        int col = n0 + wn * 64 + n * 16 + c;
        Y[(size_t)row * HD + col] = f2bu(acc[m][n][r] * sc);
      }
}

// ---------------------------------------------------------------------------
// Kernel 1b: V transpose. Vf[(b*2048+t)*512 + cc] -> Vt[(b*512+cc)*2048 + t].
// ---------------------------------------------------------------------------
__global__ __launch_bounds__(256) void vtrans_kernel(
    const ushort_t* __restrict__ Vf, ushort_t* __restrict__ Vt) {
  const int b  = blockIdx.z;
  const int t0 = blockIdx.x * 64;
  const int c0 = blockIdx.y * 64;
  __shared__ ushort_t Ls[64 * 72];
  const int tid = threadIdx.x;
  {
    int r = tid >> 2, cb = (tid & 3) * 16;
    const ushort_t* src = Vf + (size_t)(b * NQ + t0 + r) * HD + c0 + cb;
    *(int4*)(&Ls[r * 72 + cb])     = *(const int4*)src;
    *(int4*)(&Ls[r * 72 + cb + 8]) = *(const int4*)(src + 8);
  }
  __syncthreads();
  {
    int rr = tid >> 2, tb = (tid & 3) * 16;
    __align__(16) ushort_t tmp[16];
#pragma unroll
    for (int j = 0; j < 16; ++j) tmp[j] = Ls[(tb + j) * 72 + rr];
    ushort_t* dst = Vt + (size_t)(b * HD + c0 + rr) * NKK + t0 + tb;
    *(int4*)dst       = ((int4*)tmp)[0];
    *(int4*)(dst + 8) = ((int4*)tmp)[1];
  }
}

// ---------------------------------------------------------------------------
// Kernel 2: MFMA flash attention (exact round-6 form: 89 us, VGPR 100, no
// spill -- cap-256 occupancy; r7-r9 lesson: any tighter VGPR cap spills).
// ---------------------------------------------------------------------------
__global__ __launch_bounds__(256) void attn_kernel(
    const ushort_t* __restrict__ Qf, const ushort_t* __restrict__ Kf,
    const ushort_t* __restrict__ Vt, ushort_t* __restrict__ CTX) {
  const int qb = blockIdx.x;
  const int h  = blockIdx.y;
  const int b  = blockIdx.z;

  __shared__ ushort_t Kt[2 * 64 * 72];      // [buf][key][d]
  __shared__ ushort_t Vs[2 * 64 * 72];      // [buf][d][key]
  __shared__ ushort_t Ps[4 * 32 * 72];      // per-wave [q_local][key]

  const int tid  = threadIdx.x;
  const int lane = tid & 63;
  const int w    = tid >> 6;
  const int quad = lane >> 4;
  const int c    = lane & 15;

  const int q0 = qb * 128 + w * 32;

  short8 bq[2][2];
#pragma unroll
  for (int nq = 0; nq < 2; ++nq)
#pragma unroll
    for (int kk = 0; kk < 2; ++kk)
      bq[nq][kk] = *(const short8*)(Qf + (size_t)(b * NQ + q0 + nq * 16 + c) * HD +
                                    h * HS + kk * 32 + quad * 8);

  f32x4 o[2][4];
#pragma unroll
  for (int m = 0; m < 2; ++m)
#pragma unroll
    for (int n = 0; n < 4; ++n) o[m][n] = (f32x4)0.0f;
  float lsum[2] = {0.0f, 0.0f};

  ushort_t* psw = Ps + w * 32 * 72;

  int4 pk[2], pv[2];
  auto load_t = [&](int kt) {
#pragma unroll
    for (int i = 0; i < 2; ++i) {
      int g = i * 256 + tid, row = g >> 3, gr = g & 7;
      pk[i] = *(const int4*)(Kf + (size_t)(b * NKK + kt * 64 + row) * HD + h * HS + gr * 8);
      pv[i] = *(const int4*)(Vt + (size_t)((b * NH + h) * HS + row) * NKK + kt * 64 + gr * 8);
    }
  };
  auto store_t = [&](int buf) {
#pragma unroll
    for (int i = 0; i < 2; ++i) {
      int g = i * 256 + tid, row = g >> 3, gr = g & 7;
      *(int4*)(Kt + buf * 4608 + row * 72 + gr * 8) = pk[i];
      *(int4*)(Vs + buf * 4608 + row * 72 + gr * 8) = pv[i];
    }
  };

  load_t(0);
  store_t(0);
  __syncthreads();

  for (int kt = 0; kt < NKK / 64; ++kt) {
    const int cur = kt & 1;
    if (kt < NKK / 64 - 1) load_t(kt + 1);
    const ushort_t* kcur = Kt + cur * 4608;
    const ushort_t* vcur = Vs + cur * 4608;

    f32x4 s[4][2];
#pragma unroll
    for (int mk = 0; mk < 4; ++mk)
#pragma unroll
      for (int nq = 0; nq < 2; ++nq) s[mk][nq] = (f32x4)0.0f;
#pragma unroll
    for (int mk = 0; mk < 4; ++mk)
#pragma unroll
      for (int kk = 0; kk < 2; ++kk) {
        short8 ak = *(const short8*)(kcur + (mk * 16 + c) * 72 + kk * 32 + quad * 8);
#pragma unroll
        for (int nq = 0; nq < 2; ++nq)
          s[mk][nq] = __builtin_amdgcn_mfma_f32_16x16x32_bf16(ak, bq[nq][kk], s[mk][nq], 0, 0, 0);
      }

#pragma unroll
    for (int mk = 0; mk < 4; ++mk)
#pragma unroll
      for (int nq = 0; nq < 2; ++nq) {
        float p0 = __expf(s[mk][nq][0]);
        float p1 = __expf(s[mk][nq][1]);
        float p2 = __expf(s[mk][nq][2]);
        float p3 = __expf(s[mk][nq][3]);
        lsum[nq] += (p0 + p1) + (p2 + p3);
        unsigned int lo = (unsigned int)f2bu(p0) | ((unsigned int)f2bu(p1) << 16);
        unsigned int hi = (unsigned int)f2bu(p2) | ((unsigned int)f2bu(p3) << 16);
        *(uint2*)(psw + (nq * 16 + c) * 72 + mk * 16 + quad * 4) = make_uint2(lo, hi);
      }

    short8 ap[2][2];
#pragma unroll
    for (int mq = 0; mq < 2; ++mq)
#pragma unroll
      for (int kk = 0; kk < 2; ++kk)
        ap[mq][kk] = *(const short8*)(psw + (mq * 16 + c) * 72 + kk * 32 + quad * 8);
#pragma unroll
    for (int nd = 0; nd < 4; ++nd)
#pragma unroll
      for (int kk = 0; kk < 2; ++kk) {
        short8 bv = *(const short8*)(vcur + (nd * 16 + c) * 72 + kk * 32 + quad * 8);
#pragma unroll
        for (int mq = 0; mq < 2; ++mq)
          o[mq][nd] = __builtin_amdgcn_mfma_f32_16x16x32_bf16(ap[mq][kk], bv, o[mq][nd], 0, 0, 0);
      }

    if (kt < NKK / 64 - 1) store_t(cur ^ 1);
    __syncthreads();
  }

  float inv[2];
#pragma unroll
  for (int nq = 0; nq < 2; ++nq) {
    float v = lsum[nq];
    v += __shfl_xor(v, 16);
    v += __shfl_xor(v, 32);
    inv[nq] = 1.0f / v;
  }
  float invr[2][4];
#pragma unroll
  for (int mq = 0; mq < 2; ++mq)
#pragma unroll
    for (int r = 0; r < 4; ++r) invr[mq][r] = __shfl(inv[mq], quad * 4 + r);

#pragma unroll
  for (int mq = 0; mq < 2; ++mq)
#pragma unroll
    for (int nd = 0; nd < 4; ++nd)
#pragma unroll
      for (int r = 0; r < 4; ++r) {
        size_t idx = (size_t)(b * NQ + q0 + mq * 16 + quad * 4 + r) * HD +
                     h * HS + nd * 16 + c;
        CTX[idx] = f2bu(o[mq][nd][r] * invr[mq][r]);
      }
}

// ---------------------------------------------------------------------------
// Kernel 3: out[8192,64] = CTX[8192,512] @ Wh[512,64], LDS-free MFMA.
// ---------------------------------------------------------------------------
__global__ __launch_bounds__(64) void outproj_kernel(
    const ushort_t* __restrict__ CTX, const ushort_t* __restrict__ Wht,
    float* __restrict__ out) {
  const int lane = threadIdx.x & 63;
  const int quad = lane >> 4, c = lane & 15;
  const int m0 = blockIdx.x * 16;

  f32x4 o[4];
#pragma unroll
  for (int n = 0; n < 4; ++n) o[n] = (f32x4)0.0f;

  const ushort_t* arow = CTX + (size_t)(m0 + c) * HD;
#pragma unroll 4
  for (int ks = 0; ks < 16; ++ks) {
    short8 a = *(const short8*)(arow + ks * 32 + quad * 8);
#pragma unroll
    for (int nd = 0; nd < 4; ++nd) {
      short8 bn = *(const short8*)(Wht + (size_t)(nd * 16 + c) * 512 + ks * 32 + quad * 8);
      o[nd] = __builtin_amdgcn_mfma_f32_16x16x32_bf16(a, bn, o[nd], 0, 0, 0);
    }
  }
#pragma unroll
  for (int nd = 0; nd < 4; ++nd)
#pragma unroll
    for (int r = 0; r < 4; ++r)
      out[(size_t)(m0 + quad * 4 + r) * HS + nd * 16 + c] = o[nd][r];
}

// ---------------------------------------------------------------------------
extern "C" void kernel_launch(void* const* d_in, const int* in_sizes, int n_in,
                              void* d_out, int out_size, void* d_ws,
                              size_t ws_size, hipStream_t stream) {
  const float* q  = (const float*)d_in[0];
  const float* k  = (const float*)d_in[1];
  const float* Wq = (const float*)d_in[2];
  const float* Wk = (const float*)d_in[3];
  const float* Wv = (const float*)d_in[4];
  const float* Wh = (const float*)d_in[5];
  float* out = (float*)d_out;

  // Workspace (bytes). E2 = one bf16 [8192x512] tensor = 8 MiB.
  const size_t E2 = (size_t)BB * NQ * HD * 2;
  char* base = (char*)d_ws;
  ushort_t* Qf  = (ushort_t*)(base);
  ushort_t* Kf  = (ushort_t*)(base + E2);
  ushort_t* Vt  = (ushort_t*)(base + 2 * E2);
  ushort_t* CTX = (ushort_t*)(base + 3 * E2);
  ushort_t* Wt  = (ushort_t*)(base + 4 * E2);             // 1.5 MiB
  ushort_t* Wht = (ushort_t*)(base + 4 * E2 + 1572864);   // 64 KiB
  ushort_t* Vf  = (ushort_t*)(base + 4 * E2 + 1638400);   // 8 MiB
  ushort_t* Xb  = (ushort_t*)(base + 4 * E2 + 1638400 + E2);  // 16 MiB

  cvt_kernel<<<dim3(4096, 2), 256, 0, stream>>>(q, k, Xb);
  wtrans_kernel<<<dim3(8, 8, 4), 256, 0, stream>>>(Wq, Wk, Wv, Wh, Wt, Wht);
  proj_kernel<<<dim3(HD / 128, BB * NQ / 128, 3), 256, 0, stream>>>(
      Xb, Wt, Qf, Kf, Vf);
  vtrans_kernel<<<dim3(NKK / 64, HD / 64, BB), 256, 0, stream>>>(Vf, Vt);
  attn_kernel<<<dim3(NQ / 128, NH, BB), 256, 0, stream>>>(Qf, Kf, Vt, CTX);
  outproj_kernel<<<dim3(BB * NQ / 16), 64, 0, stream>>>(CTX, Wht, out);
}